// Round 6
// baseline (761.236 us; speedup 1.0000x reference)
//
#include <hip/hip_runtime.h>

// VQ: B=16, C=D=256, H=64, W=64, K=1024
#define BB 16
#define CC 256
#define HH 64
#define WW 64
#define KK 1024
#define DD 256
#define TAU 0.0625f

typedef __attribute__((ext_vector_type(8))) short bf16x8;
typedef __attribute__((ext_vector_type(4))) float f32x4;

union Frag { bf16x8 v; unsigned int u[4]; };

// trunc-split 8 consecutive floats into bf16 hi/lo fragments (pure bit-ops; x = hi + lo + O(2^-16 x))
__device__ inline void split8(const float* xp, Frag& hi, Frag& lo) {
    #pragma unroll
    for (int p = 0; p < 4; ++p) {
        const float f0 = xp[2*p], f1 = xp[2*p+1];
        const unsigned int b0 = __float_as_uint(f0), b1 = __float_as_uint(f1);
        const unsigned int h0 = b0 & 0xFFFF0000u, h1 = b1 & 0xFFFF0000u;
        const float r0 = f0 - __uint_as_float(h0);   // exact (Sterbenz)
        const float r1 = f1 - __uint_as_float(h1);
        hi.u[p] = (h0 >> 16) | h1;
        lo.u[p] = (__float_as_uint(r0) >> 16) | (__float_as_uint(r1) & 0xFFFF0000u);
    }
}

// ehalf[k] = 0.5 * ||e_k||^2, exact fp32 (one wave per row)
__global__ __launch_bounds__(256) void vq_enorm_kernel(const float* __restrict__ e,
                                                       float* __restrict__ ehalf) {
    const int wave = threadIdx.x >> 6;
    const int lane = threadIdx.x & 63;
    const int k = blockIdx.x * 4 + wave;
    const float4 v = *reinterpret_cast<const float4*>(e + (size_t)k * DD + lane * 4);
    float s = v.x * v.x + v.y * v.y + v.z * v.z + v.w * v.w;
    #pragma unroll
    for (int off = 32; off; off >>= 1) s += __shfl_xor(s, off, 64);
    if (lane == 0) ehalf[k] = 0.5f * s;
}

// emb -> bf16 trunc-split (eh, el), row-major [K][D]
__global__ __launch_bounds__(256) void vq_split_kernel(const float* __restrict__ e,
                                                       unsigned short* __restrict__ eh,
                                                       unsigned short* __restrict__ el) {
    const int idx = blockIdx.x * 256 + threadIdx.x;
    const float f = e[idx];
    const unsigned int b = __float_as_uint(f);
    const unsigned int h = b & 0xFFFF0000u;
    const float r = f - __uint_as_float(h);
    eh[idx] = (unsigned short)(h >> 16);
    el[idx] = (unsigned short)(__float_as_uint(r) >> 16);
}

// Main: one block per (b,h) = 64 tokens. score = x.e - 0.5||e||^2 via 3-term bf16 MFMA.
// Wave wv: token-tiles {ttA, ttA+1}, code-tiles [32*(wv&1), +32). Margin < TAU -> flag for rescue.
__global__ __launch_bounds__(256) void vq_mfma_kernel(
    const float* __restrict__ in, const float* __restrict__ emb,
    const float* __restrict__ ehalf,
    const unsigned short* __restrict__ ehs, const unsigned short* __restrict__ els,
    int* __restrict__ g_idx, float* __restrict__ out) {

    __shared__ float x_lds[64][260];
    __shared__ float eh_lds[KK];
    __shared__ float mg_v[64][2], mg_2[64][2];
    __shared__ int   mg_i[64][2];
    __shared__ int   idx_lds[64];

    const int tid = threadIdx.x;
    const int bid = blockIdx.x;
    const int b = bid >> 6, h = bid & 63;
    const int w = tid & 63, cs = tid >> 6;

    // ---- stage x fp32 (round-1 verbatim; stays intact for epilogue) ----
    {
        const float* src = in + (size_t)b * CC * HH * WW + (size_t)h * WW + w;
        #pragma unroll
        for (int c = cs; c < CC; c += 4) x_lds[w][c] = src[(size_t)c * (HH * WW)];
        for (int k = tid; k < KK; k += 256) eh_lds[k] = ehalf[k];
    }
    __syncthreads();

    const int wv = tid >> 6, lane = tid & 63;
    const int lr = lane & 15, lq = lane >> 4;
    const int ttA = (wv >> 1) << 1;      // 0 or 2
    const int half = wv & 1;             // ct half

    // ---- extract A fragments once: 2 tiles x 8 k-steps x (hi,lo) ----
    Frag xh[2][8], xl[2][8];
    #pragma unroll
    for (int t = 0; t < 2; ++t)
        #pragma unroll
        for (int ks = 0; ks < 8; ++ks)
            split8(&x_lds[(ttA + t) * 16 + lr][ks * 32 + lq * 8], xh[t][ks], xl[t][ks]);

    float bv[8], b2[8]; int bi[8];
    #pragma unroll
    for (int s = 0; s < 8; ++s) { bv[s] = -3.4e38f; b2[s] = -3.4e38f; bi[s] = 0; }

    const int ct0 = half * 32;
    for (int ct = ct0; ct < ct0 + 32; ++ct) {
        const int code = (ct << 4) + lr;
        const unsigned short* ep = ehs + ((size_t)code << 8) + (lq << 3);
        const unsigned short* lp = els + ((size_t)code << 8) + (lq << 3);
        Frag ef[8], lf[8];
        #pragma unroll
        for (int ks = 0; ks < 8; ++ks) {
            ef[ks].v = *reinterpret_cast<const bf16x8*>(ep + ks * 32);
            lf[ks].v = *reinterpret_cast<const bf16x8*>(lp + ks * 32);
        }
        const float nh = -eh_lds[code];
        f32x4 a0 = {nh, nh, nh, nh};
        f32x4 a1 = {nh, nh, nh, nh};
        #pragma unroll
        for (int ks = 0; ks < 8; ++ks) {
            a0 = __builtin_amdgcn_mfma_f32_16x16x32_bf16(xh[0][ks].v, ef[ks].v, a0, 0, 0, 0);
            a1 = __builtin_amdgcn_mfma_f32_16x16x32_bf16(xh[1][ks].v, ef[ks].v, a1, 0, 0, 0);
            a0 = __builtin_amdgcn_mfma_f32_16x16x32_bf16(xl[0][ks].v, ef[ks].v, a0, 0, 0, 0);
            a1 = __builtin_amdgcn_mfma_f32_16x16x32_bf16(xl[1][ks].v, ef[ks].v, a1, 0, 0, 0);
            a0 = __builtin_amdgcn_mfma_f32_16x16x32_bf16(xh[0][ks].v, lf[ks].v, a0, 0, 0, 0);
            a1 = __builtin_amdgcn_mfma_f32_16x16x32_bf16(xh[1][ks].v, lf[ks].v, a1, 0, 0, 0);
        }
        // running best/second-best (codes ascend -> strict > keeps lowest idx; tie -> margin 0 -> rescue)
        #pragma unroll
        for (int t = 0; t < 2; ++t) {
            const f32x4 av = t ? a1 : a0;
            #pragma unroll
            for (int r = 0; r < 4; ++r) {
                const float v = av[r];
                const int s = t * 4 + r;
                if (v > bv[s]) { b2[s] = bv[s]; bv[s] = v; bi[s] = code; }
                else if (v > b2[s]) b2[s] = v;
            }
        }
    }

    // ---- butterfly over the 16 code-columns (lanes differing in lr) ----
    #pragma unroll
    for (int m = 1; m < 16; m <<= 1) {
        #pragma unroll
        for (int s = 0; s < 8; ++s) {
            const float ov = __shfl_xor(bv[s], m);
            const float o2 = __shfl_xor(b2[s], m);
            const int   oi = __shfl_xor(bi[s], m);
            if (ov > bv[s] || (ov == bv[s] && oi < bi[s])) {
                b2[s] = fmaxf(bv[s], o2); bv[s] = ov; bi[s] = oi;
            } else {
                b2[s] = fmaxf(b2[s], ov);
            }
        }
    }
    if (lr == 0) {
        #pragma unroll
        for (int s = 0; s < 8; ++s) {
            const int tok = ((ttA + (s >> 2)) << 4) + (lq << 2) + (s & 3);
            mg_v[tok][half] = bv[s]; mg_2[tok][half] = b2[s]; mg_i[tok][half] = bi[s];
        }
    }
    __syncthreads();

    // ---- merge ct-halves, flag small margins ----
    if (tid < 64) {
        const float v0 = mg_v[tid][0], s0 = mg_2[tid][0]; const int i0 = mg_i[tid][0];
        const float v1 = mg_v[tid][1], s1 = mg_2[tid][1]; const int i1 = mg_i[tid][1];
        float fb, f2; int fi;
        if (v1 > v0 || (v1 == v0 && i1 < i0)) { fb = v1; fi = i1; f2 = fmaxf(v0, s1); }
        else { fb = v0; fi = i0; f2 = fmaxf(s0, v1); }
        idx_lds[tid] = fi;
        const int flag = (fb - f2 < TAU) ? (int)0x80000000 : 0;
        g_idx[(bid << 6) + tid] = fi | flag;
    }
    __syncthreads();

    // ---- epilogue (round-1 verbatim): out = x + (q - x) ----
    {
        float* dst = out + (size_t)b * CC * HH * WW + (size_t)h * WW + w;
        const float* erow = emb + (size_t)idx_lds[w] * DD;
        #pragma unroll
        for (int c = cs; c < CC; c += 4) {
            const float x = x_lds[w][c];
            const float q = erow[c];
            dst[(size_t)c * (HH * WW)] = x + (q - x);
        }
    }
}

// Rescue: recompute flagged tokens exactly (same fmaf chain as validated fp32 kernel), rewrite output.
__global__ __launch_bounds__(256) void vq_rescue_kernel(
    const float* __restrict__ in, const float* __restrict__ emb,
    const float* __restrict__ ehalf, const int* __restrict__ g_idx,
    float* __restrict__ out) {

    __shared__ int flagged[64];
    __shared__ int nflag;
    __shared__ float rv[4]; __shared__ int ri[4];
    __shared__ int fin_idx;

    const int tid = threadIdx.x, bid = blockIdx.x;
    const int b = bid >> 6, h = bid & 63;
    if (tid == 0) nflag = 0;
    __syncthreads();
    if (tid < 64) {
        if (g_idx[(bid << 6) + tid] < 0) {
            const int p = atomicAdd(&nflag, 1);
            flagged[p] = tid;
        }
    }
    __syncthreads();
    const int n = nflag;
    for (int fi_ = 0; fi_ < n; ++fi_) {
        const int w = flagged[fi_];
        const float* xr = in + (size_t)b * CC * HH * WW + (size_t)h * WW + w;
        float best = -3.4e38f; int bidx = 0;
        for (int c = tid; c < KK; c += 256) {
            float s = -ehalf[c];
            const float* er = emb + (size_t)c * DD;
            for (int d = 0; d < DD; d += 4) {
                s = fmaf(xr[(size_t)(d + 0) * (HH * WW)], er[d + 0], s);
                s = fmaf(xr[(size_t)(d + 1) * (HH * WW)], er[d + 1], s);
                s = fmaf(xr[(size_t)(d + 2) * (HH * WW)], er[d + 2], s);
                s = fmaf(xr[(size_t)(d + 3) * (HH * WW)], er[d + 3], s);
            }
            if (s > best) { best = s; bidx = c; }   // c ascending per thread
        }
        #pragma unroll
        for (int m = 1; m < 64; m <<= 1) {
            const float ov = __shfl_xor(best, m);
            const int   oi = __shfl_xor(bidx, m);
            if (ov > best || (ov == best && oi < bidx)) { best = ov; bidx = oi; }
        }
        if ((tid & 63) == 0) { rv[tid >> 6] = best; ri[tid >> 6] = bidx; }
        __syncthreads();
        if (tid == 0) {
            float fbv = rv[0]; int fbi = ri[0];
            for (int q = 1; q < 4; ++q)
                if (rv[q] > fbv || (rv[q] == fbv && ri[q] < fbi)) { fbv = rv[q]; fbi = ri[q]; }
            fin_idx = fbi;
        }
        __syncthreads();
        const int fid = fin_idx;
        const float x = in[(size_t)(b * CC + tid) * (HH * WW) + h * WW + w];
        const float q = emb[(size_t)fid * DD + tid];
        out[(size_t)(b * CC + tid) * (HH * WW) + h * WW + w] = x + (q - x);
        __syncthreads();
    }
}

// Fallback (validated round-1 fp32 path) if ws is too small for the MFMA path.
__global__ __launch_bounds__(256) void vq_fallback_kernel(
    const float* __restrict__ in, const float* __restrict__ emb,
    const float* __restrict__ ehalf, float* __restrict__ out) {

    __shared__ float x_lds[64][260];
    __shared__ float red_v[64][16];
    __shared__ int   red_i[64][16];
    __shared__ int   idx_lds[64];

    const int tid = threadIdx.x;
    const int bid = blockIdx.x;
    const int b = bid >> 6, h = bid & 63;
    const int w = tid & 63, cs = tid >> 6;
    {
        const float* src = in + (size_t)b * CC * HH * WW + (size_t)h * WW + w;
        #pragma unroll
        for (int c = cs; c < CC; c += 4) x_lds[w][c] = src[(size_t)c * (HH * WW)];
    }
    __syncthreads();
    const int i = tid & 15;
    const int j = tid >> 4;
    float best_v[4]; int best_i[4];
    #pragma unroll
    for (int t = 0; t < 4; ++t) { best_v[t] = -3.4e38f; best_i[t] = 0; }
    for (int chunk = 0; chunk < KK; chunk += 128) {
        const int c0 = chunk + j * 8;
        const float* e0 = emb + (size_t)c0 * DD;
        float acc[4][8];
        #pragma unroll
        for (int cj = 0; cj < 8; ++cj) {
            const float nh = -ehalf[c0 + cj];
            #pragma unroll
            for (int t = 0; t < 4; ++t) acc[t][cj] = nh;
        }
        #pragma unroll 2
        for (int d = 0; d < DD; d += 4) {
            float4 xv[4], ev[8];
            #pragma unroll
            for (int t = 0; t < 4; ++t)
                xv[t] = *reinterpret_cast<const float4*>(&x_lds[i + 16 * t][d]);
            #pragma unroll
            for (int cj = 0; cj < 8; ++cj)
                ev[cj] = *reinterpret_cast<const float4*>(e0 + (size_t)cj * DD + d);
            #pragma unroll
            for (int t = 0; t < 4; ++t) {
                #pragma unroll
                for (int cj = 0; cj < 8; ++cj) {
                    float a = acc[t][cj];
                    a = fmaf(xv[t].x, ev[cj].x, a);
                    a = fmaf(xv[t].y, ev[cj].y, a);
                    a = fmaf(xv[t].z, ev[cj].z, a);
                    a = fmaf(xv[t].w, ev[cj].w, a);
                    acc[t][cj] = a;
                }
            }
        }
        #pragma unroll
        for (int cj = 0; cj < 8; ++cj)
            #pragma unroll
            for (int t = 0; t < 4; ++t)
                if (acc[t][cj] > best_v[t]) { best_v[t] = acc[t][cj]; best_i[t] = c0 + cj; }
    }
    #pragma unroll
    for (int t = 0; t < 4; ++t) { red_v[i + 16 * t][j] = best_v[t]; red_i[i + 16 * t][j] = best_i[t]; }
    __syncthreads();
    if (tid < 64) {
        float bv = red_v[tid][0]; int bi = red_i[tid][0];
        #pragma unroll
        for (int jj = 1; jj < 16; ++jj) {
            const float v = red_v[tid][jj]; const int id = red_i[tid][jj];
            if (v > bv || (v == bv && id < bi)) { bv = v; bi = id; }
        }
        idx_lds[tid] = bi;
    }
    __syncthreads();
    {
        float* dst = out + (size_t)b * CC * HH * WW + (size_t)h * WW + w;
        const float* erow = emb + (size_t)idx_lds[w] * DD;
        #pragma unroll
        for (int c = cs; c < CC; c += 4) {
            const float x = x_lds[w][c];
            const float q = erow[c];
            dst[(size_t)c * (HH * WW)] = x + (q - x);
        }
    }
}

extern "C" void kernel_launch(void* const* d_in, const int* in_sizes, int n_in,
                              void* d_out, int out_size, void* d_ws, size_t ws_size,
                              hipStream_t stream) {
    const float* in  = (const float*)d_in[0];
    const float* emb = (const float*)d_in[1];
    float* out = (float*)d_out;
    char* ws = (char*)d_ws;

    float* ehalf = (float*)ws;                                    // 4 KiB
    const size_t NEED = 4096 + 2 * 524288 + 262144;               // ~1.28 MiB
    if (ws_size < NEED) {
        vq_enorm_kernel<<<KK / 4, 256, 0, stream>>>(emb, ehalf);
        vq_fallback_kernel<<<BB * HH, 256, 0, stream>>>(in, emb, ehalf, out);
        return;
    }
    unsigned short* ehs = (unsigned short*)(ws + 4096);           // 512 KiB
    unsigned short* els = (unsigned short*)(ws + 4096 + 524288);  // 512 KiB
    int* g_idx = (int*)(ws + 4096 + 2 * 524288);                  // 256 KiB

    vq_enorm_kernel<<<KK / 4, 256, 0, stream>>>(emb, ehalf);
    vq_split_kernel<<<KK, 256, 0, stream>>>(emb, ehs, els);
    vq_mfma_kernel<<<BB * HH, 256, 0, stream>>>(in, emb, ehalf, ehs, els, g_idx, out);
    vq_rescue_kernel<<<BB * HH, 256, 0, stream>>>(in, emb, ehalf, g_idx, out);
}

// Round 8
// 397.542 us; speedup vs baseline: 1.9149x; 1.9149x over previous
//
#include <hip/hip_runtime.h>

// VQ: B=16, C=D=256, H=64, W=64, K=1024
#define BB 16
#define CC 256
#define HH 64
#define WW 64
#define KK 1024
#define DD 256
#define HW (HH * WW)
#define TAU 0.0625f

typedef __attribute__((ext_vector_type(8))) short bf16x8;
typedef __attribute__((ext_vector_type(4))) float f32x4;
typedef __attribute__((ext_vector_type(16))) float f32x16;

union Frag { bf16x8 v; unsigned int u[4]; };

// trunc-split 8 floats (two float4s) into bf16 hi/lo fragments (bit-exact: x = hi + lo + O(2^-16))
__device__ inline void split8r(const float4 a, const float4 b, Frag& hi, Frag& lo) {
    float f[8] = {a.x, a.y, a.z, a.w, b.x, b.y, b.z, b.w};
    #pragma unroll
    for (int p = 0; p < 4; ++p) {
        const unsigned int b0 = __float_as_uint(f[2 * p]), b1 = __float_as_uint(f[2 * p + 1]);
        const unsigned int h0 = b0 & 0xFFFF0000u, h1 = b1 & 0xFFFF0000u;
        const float r0 = f[2 * p]     - __uint_as_float(h0);   // exact (Sterbenz)
        const float r1 = f[2 * p + 1] - __uint_as_float(h1);
        hi.u[p] = (h0 >> 16) | h1;
        lo.u[p] = (__float_as_uint(r0) >> 16) | (__float_as_uint(r1) & 0xFFFF0000u);
    }
}

__device__ inline void gld16(const void* g, void* l) {
    __builtin_amdgcn_global_load_lds(
        (const __attribute__((address_space(1))) unsigned int*)g,
        (__attribute__((address_space(3))) unsigned int*)l, 16, 0, 0);
}

__global__ void vq_zero_kernel(int* c) { *c = 0; }

// ehalf[k] = 0.5 * ||e_k||^2, exact fp32 (one wave per row)
__global__ __launch_bounds__(256) void vq_enorm_kernel(const float* __restrict__ e,
                                                       float* __restrict__ ehalf) {
    const int wave = threadIdx.x >> 6;
    const int lane = threadIdx.x & 63;
    const int k = blockIdx.x * 4 + wave;
    const float4 v = *reinterpret_cast<const float4*>(e + (size_t)k * DD + lane * 4);
    float s = v.x * v.x + v.y * v.y + v.z * v.z + v.w * v.w;
    #pragma unroll
    for (int off = 32; off; off >>= 1) s += __shfl_xor(s, off, 64);
    if (lane == 0) ehalf[k] = 0.5f * s;
}

// emb -> bf16 trunc-split (eh, el), row-major [K][D]
__global__ __launch_bounds__(256) void vq_split_kernel(const float* __restrict__ e,
                                                       unsigned short* __restrict__ eh,
                                                       unsigned short* __restrict__ el) {
    const int idx = blockIdx.x * 256 + threadIdx.x;
    const float f = e[idx];
    const unsigned int b = __float_as_uint(f);
    const unsigned int h = b & 0xFFFF0000u;
    const float r = f - __uint_as_float(h);
    eh[idx] = (unsigned short)(h >> 16);
    el[idx] = (unsigned short)(__float_as_uint(r) >> 16);
}

// Main: one block per (b,h) = 64 tokens x all 1024 codes.
// score = x.e - 0.5||e||^2 via 3-term bf16 32x32x16 MFMA; A in regs, B LDS-staged
// (lane-linear layout via pre-swizzled global source), 4-buffer counted-vmcnt pipeline.
// Wave (mg,ng): tokens mg*32..+31, codes {nt*128 + ng*64 .. +63} per nt-iteration.
__global__ __launch_bounds__(256, 2) void vq_mfma_kernel(
    const float* __restrict__ in, const float* __restrict__ emb,
    const float* __restrict__ ehalf,
    const unsigned short* __restrict__ ehs, const unsigned short* __restrict__ els,
    int* __restrict__ g_cnt, int* __restrict__ g_list,
    float* __restrict__ out) {

    __shared__ union {
        float x[64][260];            // fp32 token tile (staging + A-extraction)
        unsigned char bb[4][8192];   // B k-chunk buffers (after extraction)
    } u;
    __shared__ float eh_lds[KK];
    __shared__ float mv[64][2], m2l[64][2];
    __shared__ int   mi[64][2];
    __shared__ int   idx_lds[64];

    const int tid = threadIdx.x;
    const int bid = blockIdx.x;
    const int b = bid >> 6, h = bid & 63;
    const int w = tid & 63, cs = tid >> 6;

    // ---- stage x fp32 (coalesced over w) + eh ----
    {
        const float* src = in + (size_t)b * CC * HW + (size_t)h * WW + w;
        #pragma unroll
        for (int c = cs; c < CC; c += 4) u.x[w][c] = src[(size_t)c * HW];
        #pragma unroll
        for (int k = tid; k < KK; k += 256) eh_lds[k] = ehalf[k];
    }
    __syncthreads();

    const int lane = tid & 63;
    const int wv = tid >> 6;
    const int mg = wv >> 1, ng = wv & 1;       // compute role
    const int lc = lane & 31, lq = lane >> 5;
    const int trow = mg * 32 + lc;             // A row = lane&31

    // ---- extract A fragments once: 16 k-steps x (hi,lo) = 128 VGPRs ----
    Frag ah[16], al[16];
    #pragma unroll
    for (int ks = 0; ks < 16; ++ks) {
        const float4 v0 = *reinterpret_cast<const float4*>(&u.x[trow][ks * 16 + lq * 8]);
        const float4 v1 = *reinterpret_cast<const float4*>(&u.x[trow][ks * 16 + lq * 8 + 4]);
        split8r(v0, v1, ah[ks], al[ks]);
    }
    __syncthreads();   // x region dead -> becomes B buffers

    // ---- staging role: wave w stages (tt = w>>1, term = w&1) for both ng halves ----
    const int s_term = (tid >> 6) & 1;
    const int s_tt   = (tid >> 7) & 1;
    const unsigned short* sbase = (s_term ? els : ehs) + (size_t)(s_tt * 32 + lc) * DD + lq * 8;
    unsigned char* const dbase = &u.bb[0][0] + s_tt * 2048 + s_term * 1024 + lane * 16;
    // stage s (= nt*16+ks): src += (s>>4)*128*DD + (s&15)*16 ; dst buffer (s&3), +4096 for ng=1
    #define STAGE(s) do { \
        const unsigned short* sp_ = sbase + (((s) >> 4) << 15) + (((s) & 15) << 4); \
        unsigned char* dp_ = dbase + (((s) & 3) << 13); \
        gld16(sp_, dp_); \
        gld16(sp_ + 64 * DD, dp_ + 4096); \
    } while (0)

    STAGE(0); STAGE(1); STAGE(2);

    float bestv[16], best2[16]; int besti[16];
    #pragma unroll
    for (int r = 0; r < 16; ++r) { bestv[r] = -3.4e38f; best2[r] = -3.4e38f; besti[r] = 0; }

    for (int nt = 0; nt < 8; ++nt) {
        const int code0 = nt * 128 + ng * 64 + lc;
        f32x16 a0, a1;
        {
            const float nh0 = -eh_lds[code0];
            const float nh1 = -eh_lds[code0 + 32];
            #pragma unroll
            for (int r = 0; r < 16; ++r) { a0[r] = nh0; a1[r] = nh1; }
        }
        #pragma unroll
        for (int ks = 0; ks < 16; ++ks) {
            const int s = nt * 16 + ks;
            asm volatile("s_waitcnt vmcnt(4)" ::: "memory");
            __builtin_amdgcn_s_barrier();
            asm volatile("" ::: "memory");
            const unsigned char* bp = &u.bb[0][0] + ((s & 3) << 13) + (ng << 12) + lane * 16;
            const bf16x8 bh0 = *reinterpret_cast<const bf16x8*>(bp);
            const bf16x8 bl0 = *reinterpret_cast<const bf16x8*>(bp + 1024);
            const bf16x8 bh1 = *reinterpret_cast<const bf16x8*>(bp + 2048);
            const bf16x8 bl1 = *reinterpret_cast<const bf16x8*>(bp + 3072);
            a0 = __builtin_amdgcn_mfma_f32_32x32x16_bf16(ah[ks].v, bh0, a0, 0, 0, 0);
            a1 = __builtin_amdgcn_mfma_f32_32x32x16_bf16(ah[ks].v, bh1, a1, 0, 0, 0);
            a0 = __builtin_amdgcn_mfma_f32_32x32x16_bf16(al[ks].v, bh0, a0, 0, 0, 0);
            a1 = __builtin_amdgcn_mfma_f32_32x32x16_bf16(al[ks].v, bh1, a1, 0, 0, 0);
            a0 = __builtin_amdgcn_mfma_f32_32x32x16_bf16(ah[ks].v, bl0, a0, 0, 0, 0);
            a1 = __builtin_amdgcn_mfma_f32_32x32x16_bf16(ah[ks].v, bl1, a1, 0, 0, 0);
            // FIX: unconditional stage with wrap keeps exactly 6 loads in flight, so
            // vmcnt(4) always waits for STAGE(s). Wrap targets (buffers 0..2 at s>=125)
            // are dead by then; re-staged data is never read.
            STAGE((s + 3) & 127);
        }
        // merge this nt's scores into running (best, 2nd-best, idx) per C/D row-reg
        #pragma unroll
        for (int r = 0; r < 16; ++r) {
            const float s0 = a0[r], s1 = a1[r];
            if (s0 > bestv[r]) { best2[r] = bestv[r]; bestv[r] = s0; besti[r] = code0; }
            else if (s0 > best2[r]) best2[r] = s0;
            if (s1 > bestv[r]) { best2[r] = bestv[r]; bestv[r] = s1; besti[r] = code0 + 32; }
            else if (s1 > best2[r]) best2[r] = s1;
        }
    }
    #undef STAGE

    // ---- butterfly across the 32 code-columns (lanes differing in bits 0..4) ----
    #pragma unroll
    for (int m = 1; m < 32; m <<= 1) {
        #pragma unroll
        for (int r = 0; r < 16; ++r) {
            const float ob = __shfl_xor(bestv[r], m, 64);
            const float o2 = __shfl_xor(best2[r], m, 64);
            const int   oi = __shfl_xor(besti[r], m, 64);
            if (ob > bestv[r] || (ob == bestv[r] && oi < besti[r])) {
                best2[r] = fmaxf(bestv[r], o2); bestv[r] = ob; besti[r] = oi;
            } else {
                best2[r] = fmaxf(best2[r], ob);
            }
        }
    }
    if (lc == 0) {
        #pragma unroll
        for (int r = 0; r < 16; ++r) {
            const int row = mg * 32 + (r & 3) + 8 * (r >> 2) + 4 * lq;  // C/D row map (m74/m101)
            mv[row][ng] = bestv[r]; m2l[row][ng] = best2[r]; mi[row][ng] = besti[r];
        }
    }
    __syncthreads();

    // ---- merge ng halves per token; flag small margins into compact rescue list ----
    if (tid < 64) {
        const float v0 = mv[tid][0], s0 = m2l[tid][0]; const int i0 = mi[tid][0];
        const float v1 = mv[tid][1], s1 = m2l[tid][1]; const int i1 = mi[tid][1];
        float fb, f2; int fi;
        if (v1 > v0 || (v1 == v0 && i1 < i0)) { fb = v1; fi = i1; f2 = fmaxf(v0, s1); }
        else { fb = v0; fi = i0; f2 = fmaxf(s0, v1); }
        idx_lds[tid] = fi;
        if (fb - f2 < TAU) {
            const int p = atomicAdd(g_cnt, 1);
            g_list[p] = (bid << 6) + tid;
        }
    }
    __syncthreads();

    // ---- epilogue: out = x + (q - x), x re-read from global (coalesced) ----
    {
        const float* srcx = in + (size_t)b * CC * HW + (size_t)h * WW + w;
        float* dst = out + (size_t)b * CC * HW + (size_t)h * WW + w;
        const float* erow = emb + (size_t)idx_lds[w] * DD;
        #pragma unroll
        for (int c = cs; c < CC; c += 4) {
            const float x = srcx[(size_t)c * HW];
            const float q = erow[c];
            dst[(size_t)c * HW] = x + (q - x);
        }
    }
}

// Rescue: one flagged token per block iteration, exact fp32 fmaf chain, rewrite output.
__global__ __launch_bounds__(256) void vq_rescue_kernel(
    const float* __restrict__ in, const float* __restrict__ emb,
    const float* __restrict__ ehalf, const int* __restrict__ g_cnt,
    const int* __restrict__ g_list, float* __restrict__ out) {

    __shared__ float xs[DD];
    __shared__ float rv[4]; __shared__ int ri[4];
    __shared__ int fin;

    const int tid = threadIdx.x;
    const int n = *g_cnt;
    for (int li = blockIdx.x; li < n; li += (int)gridDim.x) {
        const int tok = g_list[li];
        const int b = tok >> 12, h = (tok >> 6) & 63, w = tok & 63;
        xs[tid] = in[(size_t)(b * CC + tid) * HW + h * WW + w];
        __syncthreads();
        float best = -3.4e38f; int bidx = 0;
        #pragma unroll
        for (int cc = 0; cc < 4; ++cc) {
            const int code = tid * 4 + cc;                 // ascending per thread
            float sc = -ehalf[code];
            const float* er = emb + (size_t)code * DD;
            for (int d = 0; d < DD; d += 4) {
                sc = fmaf(xs[d + 0], er[d + 0], sc);
                sc = fmaf(xs[d + 1], er[d + 1], sc);
                sc = fmaf(xs[d + 2], er[d + 2], sc);
                sc = fmaf(xs[d + 3], er[d + 3], sc);
            }
            if (sc > best) { best = sc; bidx = code; }
        }
        #pragma unroll
        for (int m = 1; m < 64; m <<= 1) {
            const float ov = __shfl_xor(best, m, 64);
            const int   oi = __shfl_xor(bidx, m, 64);
            if (ov > best || (ov == best && oi < bidx)) { best = ov; bidx = oi; }
        }
        if ((tid & 63) == 0) { rv[tid >> 6] = best; ri[tid >> 6] = bidx; }
        __syncthreads();
        if (tid == 0) {
            float fb = rv[0]; int fi2 = ri[0];
            #pragma unroll
            for (int q2 = 1; q2 < 4; ++q2)
                if (rv[q2] > fb || (rv[q2] == fb && ri[q2] < fi2)) { fb = rv[q2]; fi2 = ri[q2]; }
            fin = fi2;
        }
        __syncthreads();
        const int fid = fin;
        const float xv = xs[tid];
        const float qv = emb[(size_t)fid * DD + tid];
        out[(size_t)(b * CC + tid) * HW + h * WW + w] = xv + (qv - xv);
        __syncthreads();
    }
}

// Fallback (validated fp32 VALU path) if ws is too small.
__global__ __launch_bounds__(256) void vq_fallback_kernel(
    const float* __restrict__ in, const float* __restrict__ emb,
    const float* __restrict__ ehalf, float* __restrict__ out) {

    __shared__ float x_lds[64][260];
    __shared__ float red_v[64][16];
    __shared__ int   red_i[64][16];
    __shared__ int   idx_lds[64];

    const int tid = threadIdx.x;
    const int bid = blockIdx.x;
    const int b = bid >> 6, h = bid & 63;
    const int w = tid & 63, cs = tid >> 6;
    {
        const float* src = in + (size_t)b * CC * HW + (size_t)h * WW + w;
        #pragma unroll
        for (int c = cs; c < CC; c += 4) x_lds[w][c] = src[(size_t)c * HW];
    }
    __syncthreads();
    const int i = tid & 15;
    const int j = tid >> 4;
    float best_v[4]; int best_i[4];
    #pragma unroll
    for (int t = 0; t < 4; ++t) { best_v[t] = -3.4e38f; best_i[t] = 0; }
    for (int chunk = 0; chunk < KK; chunk += 128) {
        const int c0 = chunk + j * 8;
        const float* e0 = emb + (size_t)c0 * DD;
        float acc[4][8];
        #pragma unroll
        for (int cj = 0; cj < 8; ++cj) {
            const float nh = -ehalf[c0 + cj];
            #pragma unroll
            for (int t = 0; t < 4; ++t) acc[t][cj] = nh;
        }
        #pragma unroll 2
        for (int d = 0; d < DD; d += 4) {
            float4 xv[4], ev[8];
            #pragma unroll
            for (int t = 0; t < 4; ++t)
                xv[t] = *reinterpret_cast<const float4*>(&x_lds[i + 16 * t][d]);
            #pragma unroll
            for (int cj = 0; cj < 8; ++cj)
                ev[cj] = *reinterpret_cast<const float4*>(e0 + (size_t)cj * DD + d);
            #pragma unroll
            for (int t = 0; t < 4; ++t) {
                #pragma unroll
                for (int cj = 0; cj < 8; ++cj) {
                    float a = acc[t][cj];
                    a = fmaf(xv[t].x, ev[cj].x, a);
                    a = fmaf(xv[t].y, ev[cj].y, a);
                    a = fmaf(xv[t].z, ev[cj].z, a);
                    a = fmaf(xv[t].w, ev[cj].w, a);
                    acc[t][cj] = a;
                }
            }
        }
        #pragma unroll
        for (int cj = 0; cj < 8; ++cj)
            #pragma unroll
            for (int t = 0; t < 4; ++t)
                if (acc[t][cj] > best_v[t]) { best_v[t] = acc[t][cj]; best_i[t] = c0 + cj; }
    }
    #pragma unroll
    for (int t = 0; t < 4; ++t) { red_v[i + 16 * t][j] = best_v[t]; red_i[i + 16 * t][j] = best_i[t]; }
    __syncthreads();
    if (tid < 64) {
        float bv = red_v[tid][0]; int bi = red_i[tid][0];
        #pragma unroll
        for (int jj = 1; jj < 16; ++jj) {
            const float v = red_v[tid][jj]; const int id = red_i[tid][jj];
            if (v > bv || (v == bv && id < bi)) { bv = v; bi = id; }
        }
        idx_lds[tid] = bi;
    }
    __syncthreads();
    {
        float* dst = out + (size_t)b * CC * HW + (size_t)h * WW + w;
        const float* erow = emb + (size_t)idx_lds[w] * DD;
        #pragma unroll
        for (int c = cs; c < CC; c += 4) {
            const float x = x_lds[w][c];
            const float q = erow[c];
            dst[(size_t)c * HW] = x + (q - x);
        }
    }
}

extern "C" void kernel_launch(void* const* d_in, const int* in_sizes, int n_in,
                              void* d_out, int out_size, void* d_ws, size_t ws_size,
                              hipStream_t stream) {
    const float* in  = (const float*)d_in[0];
    const float* emb = (const float*)d_in[1];
    float* out = (float*)d_out;
    char* ws = (char*)d_ws;

    float* ehalf = (float*)ws;                                        // 4 KiB
    const size_t OFF_EHS  = 4096;
    const size_t OFF_ELS  = OFF_EHS + (size_t)KK * DD * 2;            // +512 KiB
    const size_t OFF_CNT  = OFF_ELS + (size_t)KK * DD * 2;            // +512 KiB
    const size_t OFF_LIST = OFF_CNT + 128;
    const size_t NEED     = OFF_LIST + (size_t)BB * HH * WW * 4;      // +256 KiB

    if (ws_size < NEED) {
        vq_enorm_kernel<<<KK / 4, 256, 0, stream>>>(emb, ehalf);
        vq_fallback_kernel<<<BB * HH, 256, 0, stream>>>(in, emb, ehalf, out);
        return;
    }
    unsigned short* ehs = (unsigned short*)(ws + OFF_EHS);
    unsigned short* els = (unsigned short*)(ws + OFF_ELS);
    int* g_cnt  = (int*)(ws + OFF_CNT);
    int* g_list = (int*)(ws + OFF_LIST);

    vq_zero_kernel<<<1, 1, 0, stream>>>(g_cnt);
    vq_enorm_kernel<<<KK / 4, 256, 0, stream>>>(emb, ehalf);
    vq_split_kernel<<<KK, 256, 0, stream>>>(emb, ehs, els);
    vq_mfma_kernel<<<BB * HH, 256, 0, stream>>>(in, emb, ehalf, ehs, els, g_cnt, g_list, out);
    vq_rescue_kernel<<<256, 256, 0, stream>>>(in, emb, ehalf, g_cnt, g_list, out);
}